// Round 7
// baseline (200.038 us; speedup 1.0000x reference)
//
#include <hip/hip_runtime.h>

typedef __bf16 bf16;
typedef __bf16 bf16x2 __attribute__((ext_vector_type(2)));
typedef __bf16 bf16x4 __attribute__((ext_vector_type(4)));
typedef __bf16 bf16x8 __attribute__((ext_vector_type(8)));
typedef float f32x4 __attribute__((ext_vector_type(4)));

#define MFMA16(a, b, c) __builtin_amdgcn_mfma_f32_16x16x32_bf16((a), (b), (c), 0, 0, 0)

// 0.125 (attn scale) * log2(e): folded into Q projection so softmax is exp2(s).
#define QSCALE 0.18033688011112042f

// async global->LDS, 16 B per lane. LDS dest = wave-uniform base + lane*16.
__device__ inline void gld16(const void* g, void* l) {
    __builtin_amdgcn_global_load_lds(
        (const __attribute__((address_space(1))) unsigned int*)g,
        (__attribute__((address_space(3))) unsigned int*)l, 16, 0, 0);
}

__device__ inline bf16x8 cvt8(float4 a, float4 b) {
    bf16x8 v;
    v[0] = (bf16)a.x; v[1] = (bf16)a.y; v[2] = (bf16)a.z; v[3] = (bf16)a.w;
    v[4] = (bf16)b.x; v[5] = (bf16)b.y; v[6] = (bf16)b.z; v[7] = (bf16)b.w;
    return v;
}

// ---------------------------------------------------------------------------
// fp32 -> bf16: grid dim3(2048,4), every block full (no dead blocks).
// y=0,1,2 -> q,k,v (4M elems each). y=3 -> the four 1M-elem weights packed:
// wsel = i>>20 picks wq/wk/wv/wo.
// ---------------------------------------------------------------------------
__global__ __launch_bounds__(256) void cvt7_kernel(
    const float* __restrict__ q,  bf16* __restrict__ qb,
    const float* __restrict__ k,  bf16* __restrict__ kb,
    const float* __restrict__ v,  bf16* __restrict__ vb,
    const float* __restrict__ wq, bf16* __restrict__ wqb,
    const float* __restrict__ wk, bf16* __restrict__ wkb,
    const float* __restrict__ wv, bf16* __restrict__ wvb,
    const float* __restrict__ wo, bf16* __restrict__ wob)
{
    int i = (blockIdx.x * 256 + threadIdx.x) * 8;
    const float* src; bf16* dst;
    switch (blockIdx.y) {
        case 0: src = q; dst = qb; break;
        case 1: src = k; dst = kb; break;
        case 2: src = v; dst = vb; break;
        default: {
            int wsel = i >> 20;                 // 0..3
            int off  = i & ((1 << 20) - 1);
            src = wsel == 0 ? wq : wsel == 1 ? wk : wsel == 2 ? wv : wo;
            dst = wsel == 0 ? wqb : wsel == 1 ? wkb : wsel == 2 ? wvb : wob;
            float4 a = *(const float4*)&src[off];
            float4 b = *(const float4*)&src[off + 4];
            *(bf16x8*)&dst[off] = cvt8(a, b);
            return;
        }
    }
    float4 a = *(const float4*)&src[i];
    float4 b = *(const float4*)&src[i + 4];
    *(bf16x8*)&dst[i] = cvt8(a, b);
}

__global__ __launch_bounds__(256) void cvt3_kernel(
    const float* __restrict__ s0, bf16* __restrict__ d0,
    const float* __restrict__ s1, bf16* __restrict__ d1,
    const float* __restrict__ s2, bf16* __restrict__ d2)
{
    const float* src = blockIdx.y == 0 ? s0 : blockIdx.y == 1 ? s1 : s2;
    bf16*        dst = blockIdx.y == 0 ? d0 : blockIdx.y == 1 ? d1 : d2;
    int i = (blockIdx.x * 256 + threadIdx.x) * 8;
    float4 a = *(const float4*)&src[i];
    float4 b = *(const float4*)&src[i + 4];
    *(bf16x8*)&dst[i] = cvt8(a, b);
}

__global__ __launch_bounds__(256) void cvt_kernel(
    const float* __restrict__ src, bf16* __restrict__ dst, int n)
{
    int i = (blockIdx.x * 256 + threadIdx.x) * 8;
    if (i < n) {
        float4 a = *(const float4*)&src[i];
        float4 b = *(const float4*)&src[i + 4];
        *(bf16x8*)&dst[i] = cvt8(a, b);
    }
}

// ---------------------------------------------------------------------------
// Pure-bf16 fused QKV projection (fast path), m97-form: both operands staged
// with global_load_lds into single-buffered swizzled LDS, 2 barriers/iter;
// latency hidden by cross-block overlap. Grid 768 XCD-swizzled.
// proj0 -> Qp (scaled), proj1 -> Kp, proj2 -> Vt[bh][d][t64*64+kv'],
// kv' = (s&15)*4 + (s>>4), via LDS transpose.
// ---------------------------------------------------------------------------
__global__ __launch_bounds__(256) void qkv_bf16(
    const bf16* __restrict__ qb, const bf16* __restrict__ kb,
    const bf16* __restrict__ vb,
    const bf16* __restrict__ wq, const float* __restrict__ bq,
    const bf16* __restrict__ wk, const float* __restrict__ bk,
    const bf16* __restrict__ wv, const float* __restrict__ bv,
    bf16* __restrict__ Qp, bf16* __restrict__ Kp, bf16* __restrict__ Vt)
{
    __shared__ __align__(16) bf16 sm[16896];   // As(8192)+Bs(8192); Ts alias 16896
    bf16* As = sm;
    bf16* Bs = sm + 8192;
    bf16* Ts = sm;                             // epilogue transpose [128][132]

    const int id  = blockIdx.x;
    const int pr  = (id >> 6) * 8 + (id & 7);  // proj*32+row, 0..95
    const int proj = pr >> 5;
    const int m0  = (pr & 31) * 128;
    const int n0  = ((id >> 3) & 7) * 128;

    const bf16*  A    = proj == 0 ? qb : proj == 1 ? kb : vb;
    const bf16*  B    = proj == 0 ? wq : proj == 1 ? wk : wv;
    const float* bias = proj == 0 ? bq : proj == 1 ? bk : bv;

    const int tid  = threadIdx.x;
    const int lane = tid & 63;
    const int w    = tid >> 6;
    const int g    = lane >> 4;
    const int ln   = lane & 15;
    const int rowb = (w & 1) * 64;
    const int colb = (w >> 1) * 64;
    const int ro   = lane >> 3, lc = lane & 7;

    auto issue = [&](int t) {
        int k0 = t * 64;
        for (int j = 0; j < 4; ++j) {
            int base = w * 32 + j * 8;
            int row  = base + ro;
            int c    = lc ^ (row & 7);
            gld16(&A[(size_t)(m0 + row) * 1024 + k0 + c * 8], &As[base * 64]);
            gld16(&B[(size_t)(n0 + row) * 1024 + k0 + c * 8], &Bs[base * 64]);
        }
    };

    issue(0);
    f32x4 acc[4][4] = {};

    for (int t = 0; t < 16; ++t) {
        __syncthreads();                 // drains gld(t): LDS valid
        for (int ks = 0; ks < 2; ++ks) {
            bf16x8 af[4], bfm[4];
            for (int mi = 0; mi < 4; ++mi) {
                int row = rowb + mi * 16 + ln;
                af[mi] = *(const bf16x8*)&As[row * 64 + ((ks * 4 + g) ^ (ln & 7)) * 8];
            }
            for (int ni = 0; ni < 4; ++ni) {
                int row = colb + ni * 16 + ln;
                bfm[ni] = *(const bf16x8*)&Bs[row * 64 + ((ks * 4 + g) ^ (ln & 7)) * 8];
            }
            for (int mi = 0; mi < 4; ++mi)
                for (int ni = 0; ni < 4; ++ni)
                    acc[mi][ni] = MFMA16(af[mi], bfm[ni], acc[mi][ni]);
        }
        __syncthreads();                 // all waves done reading tile t
        if (t < 15) issue(t + 1);
    }

    if (proj != 2) {
        for (int mi = 0; mi < 4; ++mi) {
            for (int ni = 0; ni < 4; ++ni) {
                int col = n0 + colb + ni * 16 + ln;
                float bv_ = bias[col];
                int rowbase = m0 + rowb + mi * 16 + g * 4;
                if (proj == 0) {
                    for (int r = 0; r < 4; ++r)
                        Qp[(size_t)(rowbase + r) * 1024 + col] =
                            (bf16)((acc[mi][ni][r] + bv_) * QSCALE);
                } else {
                    for (int r = 0; r < 4; ++r)
                        Kp[(size_t)(rowbase + r) * 1024 + col] =
                            (bf16)(acc[mi][ni][r] + bv_);
                }
            }
        }
    } else {
        for (int mi = 0; mi < 4; ++mi) {
            for (int ni = 0; ni < 4; ++ni) {
                int col = colb + ni * 16 + ln;
                float bv_ = bias[n0 + col];
                int row = rowb + mi * 16 + g * 4;
                bf16x4 pk;
                for (int r = 0; r < 4; ++r) pk[r] = (bf16)(acc[mi][ni][r] + bv_);
                *(bf16x4*)&Ts[col * 132 + row] = pk;
            }
        }
        __syncthreads();
        const int bidx = m0 >> 11;
        const int tok0 = m0 & 2047;
        for (int i = 0; i < 8; ++i) {
            int c    = tid + 256 * i;
            int col  = c >> 4;
            int t64  = (c >> 3) & 1;
            int cc   = c & 7;
            int gcol = n0 + col;
            union { bf16 e[8]; uint4 u; } tmp;
            for (int j = 0; j < 8; ++j) {
                int s = 2 * cc + (j >> 2) + ((j & 3) << 4);
                tmp.e[j] = Ts[col * 132 + t64 * 64 + s];
            }
            size_t dst = ((size_t)(bidx * 16 + (gcol >> 6)) * 64 + (gcol & 63)) * 2048
                         + tok0 + t64 * 64 + cc * 8;
            *(uint4*)&Vt[dst] = tmp.u;
        }
    }
}

// ---------------------------------------------------------------------------
// Fallback QKV (ws too small): r7's fp32-A register staging + bf16-B gld16.
// ---------------------------------------------------------------------------
__global__ __launch_bounds__(256) void qkv_gemm(
    const float* __restrict__ q, const float* __restrict__ k,
    const float* __restrict__ v,
    const bf16* __restrict__ wq, const float* __restrict__ bq,
    const bf16* __restrict__ wk, const float* __restrict__ bk,
    const bf16* __restrict__ wv, const float* __restrict__ bv,
    bf16* __restrict__ Qp, bf16* __restrict__ Kp, bf16* __restrict__ Vt)
{
    __shared__ __align__(16) bf16 sm[8192 + 2 * 8192];
    bf16* As = sm;
    bf16* Bs = sm + 8192;
    bf16* Ts = sm;

    const int id  = blockIdx.x;
    const int pr  = (id >> 6) * 8 + (id & 7);
    const int proj = pr >> 5;
    const int m0  = (pr & 31) * 128;
    const int n0  = ((id >> 3) & 7) * 128;

    const float* A    = proj == 0 ? q  : proj == 1 ? k  : v;
    const bf16*  B    = proj == 0 ? wq : proj == 1 ? wk : wv;
    const float* bias = proj == 0 ? bq : proj == 1 ? bk : bv;

    const int tid  = threadIdx.x;
    const int lane = tid & 63;
    const int w    = tid >> 6;
    const int g    = lane >> 4;
    const int ln   = lane & 15;
    const int rowb = (w & 1) * 64;
    const int colb = (w >> 1) * 64;
    const int srow = tid >> 3, slc = tid & 7;
    const int ro   = lane >> 3, lc = lane & 7;

    float4 ra[4][2];
    for (int i = 0; i < 4; ++i) {
        const float* p = &A[(size_t)(m0 + srow + 32 * i) * 1024 + slc * 8];
        ra[i][0] = *(const float4*)p;
        ra[i][1] = *(const float4*)(p + 4);
    }
    for (int j = 0; j < 4; ++j) {
        int base = w * 32 + j * 8;
        int row  = base + ro;
        int c    = lc ^ (row & 7);
        gld16(&B[(size_t)(n0 + row) * 1024 + c * 8], &Bs[base * 64]);
    }

    f32x4 acc[4][4] = {};

    for (int t = 0; t < 16; ++t) {
        __syncthreads();
        for (int i = 0; i < 4; ++i) {
            int row = srow + 32 * i;
            *(bf16x8*)&As[row * 64 + (slc ^ (row & 7)) * 8] = cvt8(ra[i][0], ra[i][1]);
        }
        __syncthreads();
        if (t < 15) {
            int k1 = (t + 1) * 64;
            for (int i = 0; i < 4; ++i) {
                const float* p = &A[(size_t)(m0 + srow + 32 * i) * 1024 + k1 + slc * 8];
                ra[i][0] = *(const float4*)p;
                ra[i][1] = *(const float4*)(p + 4);
            }
            int bsel = (t + 1) & 1;
            for (int j = 0; j < 4; ++j) {
                int base = w * 32 + j * 8;
                int row  = base + ro;
                int c    = lc ^ (row & 7);
                gld16(&B[(size_t)(n0 + row) * 1024 + k1 + c * 8],
                      &Bs[bsel * 8192 + base * 64]);
            }
        }
        const bf16* Bt = Bs + (t & 1) * 8192;
        for (int ks = 0; ks < 2; ++ks) {
            bf16x8 af[4], bfm[4];
            for (int mi = 0; mi < 4; ++mi) {
                int row = rowb + mi * 16 + ln;
                af[mi] = *(const bf16x8*)&As[row * 64 + ((ks * 4 + g) ^ (ln & 7)) * 8];
            }
            for (int ni = 0; ni < 4; ++ni) {
                int row = colb + ni * 16 + ln;
                bfm[ni] = *(const bf16x8*)&Bt[row * 64 + ((ks * 4 + g) ^ (ln & 7)) * 8];
            }
            for (int mi = 0; mi < 4; ++mi)
                for (int ni = 0; ni < 4; ++ni)
                    acc[mi][ni] = MFMA16(af[mi], bfm[ni], acc[mi][ni]);
        }
    }

    if (proj != 2) {
        for (int mi = 0; mi < 4; ++mi) {
            for (int ni = 0; ni < 4; ++ni) {
                int col = n0 + colb + ni * 16 + ln;
                float bv_ = bias[col];
                int rowbase = m0 + rowb + mi * 16 + g * 4;
                if (proj == 0) {
                    for (int r = 0; r < 4; ++r)
                        Qp[(size_t)(rowbase + r) * 1024 + col] =
                            (bf16)((acc[mi][ni][r] + bv_) * QSCALE);
                } else {
                    for (int r = 0; r < 4; ++r)
                        Kp[(size_t)(rowbase + r) * 1024 + col] =
                            (bf16)(acc[mi][ni][r] + bv_);
                }
            }
        }
    } else {
        __syncthreads();
        for (int mi = 0; mi < 4; ++mi) {
            for (int ni = 0; ni < 4; ++ni) {
                int col = colb + ni * 16 + ln;
                float bv_ = bias[n0 + col];
                int row = rowb + mi * 16 + g * 4;
                bf16x4 pk;
                for (int r = 0; r < 4; ++r) pk[r] = (bf16)(acc[mi][ni][r] + bv_);
                *(bf16x4*)&Ts[col * 132 + row] = pk;
            }
        }
        __syncthreads();
        const int bidx = m0 >> 11;
        const int tok0 = m0 & 2047;
        for (int i = 0; i < 8; ++i) {
            int c    = tid + 256 * i;
            int col  = c >> 4;
            int t64  = (c >> 3) & 1;
            int cc   = c & 7;
            int gcol = n0 + col;
            union { bf16 e[8]; uint4 u; } tmp;
            for (int j = 0; j < 8; ++j) {
                int s = 2 * cc + (j >> 2) + ((j & 3) << 4);
                tmp.e[j] = Ts[col * 132 + t64 * 64 + s];
            }
            size_t dst = ((size_t)(bidx * 16 + (gcol >> 6)) * 64 + (gcol & 63)) * 2048
                         + tok0 + t64 * 64 + cc * 8;
            *(uint4*)&Vt[dst] = tmp.u;
        }
    }
}

// ---------------------------------------------------------------------------
// Output projection: C[4096,1024] fp32 = Ctx(bf16) @ wo^T(bf16) + bo.
// 64x128 tiles, grid 512, both operands dbuf global_load_lds, 1 barrier/iter.
// ---------------------------------------------------------------------------
__global__ __launch_bounds__(256) void gemm_out(
    const bf16* __restrict__ A, const bf16* __restrict__ B,
    const float* __restrict__ bias, float* __restrict__ C)
{
    __shared__ __align__(16) bf16 sm[2 * 4096 + 2 * 8192];
    bf16* As = sm;
    bf16* Bs = sm + 8192;

    const int id = blockIdx.x;
    const int m0 = ((id >> 6) * 8 + (id & 7)) * 64;
    const int n0 = ((id >> 3) & 7) * 128;

    const int tid  = threadIdx.x;
    const int lane = tid & 63;
    const int w    = tid >> 6;
    const int g    = lane >> 4;
    const int ln   = lane & 15;
    const int rowb = (w & 1) * 32;
    const int colb = (w >> 1) * 64;
    const int ro   = lane >> 3, lc = lane & 7;

    auto issue = [&](int t) {
        int k0 = t * 64, sel = t & 1;
        for (int j = 0; j < 2; ++j) {
            int base = w * 16 + j * 8;
            int row  = base + ro;
            int c    = lc ^ (row & 7);
            gld16(&A[(size_t)(m0 + row) * 1024 + k0 + c * 8],
                  &As[sel * 4096 + base * 64]);
        }
        for (int j = 0; j < 4; ++j) {
            int base = w * 32 + j * 8;
            int row  = base + ro;
            int c    = lc ^ (row & 7);
            gld16(&B[(size_t)(n0 + row) * 1024 + k0 + c * 8],
                  &Bs[sel * 8192 + base * 64]);
        }
    };

    issue(0);
    f32x4 acc[2][4] = {};

    for (int t = 0; t < 16; ++t) {
        __syncthreads();
        if (t < 15) issue(t + 1);
        const bf16* At = As + (t & 1) * 4096;
        const bf16* Bt = Bs + (t & 1) * 8192;
        for (int ks = 0; ks < 2; ++ks) {
            bf16x8 af[2], bfm[4];
            for (int mi = 0; mi < 2; ++mi) {
                int row = rowb + mi * 16 + ln;
                af[mi] = *(const bf16x8*)&At[row * 64 + ((ks * 4 + g) ^ (ln & 7)) * 8];
            }
            for (int ni = 0; ni < 4; ++ni) {
                int row = colb + ni * 16 + ln;
                bfm[ni] = *(const bf16x8*)&Bt[row * 64 + ((ks * 4 + g) ^ (ln & 7)) * 8];
            }
            for (int mi = 0; mi < 2; ++mi)
                for (int ni = 0; ni < 4; ++ni)
                    acc[mi][ni] = MFMA16(af[mi], bfm[ni], acc[mi][ni]);
        }
    }

    for (int mi = 0; mi < 2; ++mi) {
        for (int ni = 0; ni < 4; ++ni) {
            int col = n0 + colb + ni * 16 + ln;
            float bv_ = bias[col];
            int rowbase = m0 + rowb + mi * 16 + g * 4;
            for (int r = 0; r < 4; ++r)
                C[(size_t)(rowbase + r) * 1024 + col] = acc[mi][ni][r] + bv_;
        }
    }
}

// ---------------------------------------------------------------------------
// Flash attention (no-max softmax; logits pre-scaled -> exp2). 128-row q-tiles,
// 512-thread blocks: waves 0-3 do KV[0:1024], waves 4-7 KV[1024:2048] for the
// SAME 128 q-rows (partials combine by plain addition in an LDS epilogue).
// Grid 512 XCD-swizzled, 2 blocks/CU (LDS 64 KiB). [R5-proven version]
// ---------------------------------------------------------------------------
__global__ __launch_bounds__(512, 4) void attn_kernel(
    const bf16* __restrict__ Qp, const bf16* __restrict__ Kp,
    const bf16* __restrict__ Vt, bf16* __restrict__ Ctx)
{
    __shared__ __align__(16) bf16 smem[32768];   // 64 KiB
    bf16* Ks = smem;               // [grp*2+sel][64][64]  [kv][d]
    bf16* Vs = smem + 16384;       // [grp*2+sel][64][64]  [d][kv']
    float* O_sh = (float*)smem;            // epilogue alias [64][132]
    float* l_sh = (float*)smem + 64 * 132; // epilogue alias [128]

    const int id = blockIdx.x;                     // 0..511
    const int qt = (id >> 3) & 15;                 // 0..15 (128-row q-tiles)
    const int bh = (id & 7) + ((id >> 7) << 3);    // 0..31, id%8 = XCD

    const int tid  = threadIdx.x;
    const int lane = tid & 63;
    const int w    = tid >> 6;     // 0..7
    const int h    = w >> 2;       // KV half (0: rows 0..1023, 1: 1024..2047)
    const int wl   = w & 3;        // wave within group
    const int g    = lane >> 4;
    const int ln   = lane & 15;
    const int ro   = lane >> 3, lc = lane & 7;
    const int kvb  = h * 1024;
    const size_t rowQ0 = (size_t)(bh >> 4) * 2048 + qt * 128;
    const size_t rowK0 = (size_t)(bh >> 4) * 2048;
    const int hcol = (bh & 15) * 64;
    const bf16* VtB = Vt + (size_t)bh * 64 * 2048;

    // stage KV tile 0 of this group's half (each wave: 16 rows of K and V)
    for (int j = 0; j < 2; ++j) {
        int base = wl * 16 + j * 8;
        int row  = base + ro;
        int c    = lc ^ (row & 7);
        gld16(&Kp[(rowK0 + kvb + row) * 1024 + hcol + c * 8],
              &Ks[(h * 2 + 0) * 4096 + base * 64]);
        gld16(&VtB[(size_t)row * 2048 + kvb + c * 8],
              &Vs[(h * 2 + 0) * 4096 + base * 64]);
    }

    // Q fragments straight from global, two 16-row groups per wave.
    // Both KV-halves load the SAME q-rows (q = wl*32 + u*16 + ln).
    bf16x8 qf[2][2];
#pragma unroll
    for (int u = 0; u < 2; ++u)
#pragma unroll
        for (int ks = 0; ks < 2; ++ks)
            qf[u][ks] = *(const bf16x8*)&Qp[(rowQ0 + wl * 32 + u * 16 + ln) * 1024
                                            + hcol + ks * 32 + g * 8];

    bf16x8 ones;
#pragma unroll
    for (int i = 0; i < 8; ++i) ones[i] = (bf16)1.0f;

    f32x4 oacc[2][4] = {};
    f32x4 lacc[2] = {};

    __syncthreads();

    for (int t = 0; t < 16; ++t) {
        if (t < 15) {                  // t+1 KV flies through this tile's compute
            int sel = (t + 1) & 1, kvo = kvb + (t + 1) * 64;
            for (int j = 0; j < 2; ++j) {
                int base = wl * 16 + j * 8;
                int row  = base + ro;
                int c    = lc ^ (row & 7);
                gld16(&Kp[(rowK0 + kvo + row) * 1024 + hcol + c * 8],
                      &Ks[(h * 2 + sel) * 4096 + base * 64]);
                gld16(&VtB[(size_t)row * 2048 + kvo + c * 8],
                      &Vs[(h * 2 + sel) * 4096 + base * 64]);
            }
        }
        const bf16* Kt  = Ks + (h * 2 + (t & 1)) * 4096;
        const bf16* Vti = Vs + (h * 2 + (t & 1)) * 4096;

        // S^T = K Q^T (pre-scaled): sf[u][nj][r] = S[q=ln(u)][kv=nj*16+g*4+r]
        f32x4 sf[2][4] = {};
#pragma unroll
        for (int ks = 0; ks < 2; ++ks) {
            bf16x8 kf[4];
#pragma unroll
            for (int nj = 0; nj < 4; ++nj) {
                int row = nj * 16 + ln;
                kf[nj] = *(const bf16x8*)&Kt[row * 64 + ((ks * 4 + g) ^ (ln & 7)) * 8];
            }
            __builtin_amdgcn_s_setprio(1);
#pragma unroll
            for (int u = 0; u < 2; ++u)
#pragma unroll
                for (int nj = 0; nj < 4; ++nj)
                    sf[u][nj] = MFMA16(kf[nj], qf[u][ks], sf[u][nj]);
            __builtin_amdgcn_s_setprio(0);
        }

        // P = exp2(S), packed along nj: W[u][r][h] = cvt_pk(p[2h][r], p[2h+1][r])
        unsigned W[2][4][2];
#pragma unroll
        for (int u = 0; u < 2; ++u)
#pragma unroll
            for (int r = 0; r < 4; ++r)
#pragma unroll
                for (int hh = 0; hh < 2; ++hh) {
                    bf16x2 t2;
                    t2[0] = (bf16)__builtin_amdgcn_exp2f(sf[u][2 * hh][r]);
                    t2[1] = (bf16)__builtin_amdgcn_exp2f(sf[u][2 * hh + 1][r]);
                    W[u][r][hh] = __builtin_bit_cast(unsigned, t2);
                }
        // Route to PV A-fragment order (matches Vt token permutation).
#pragma unroll
        for (int u = 0; u < 2; ++u)
#pragma unroll
            for (int hh = 0; hh < 2; ++hh) {
                asm("v_permlane16_swap_b32 %0, %1" : "+v"(W[u][0][hh]), "+v"(W[u][2][hh]));
                asm("v_permlane32_swap_b32 %0, %1" : "+v"(W[u][0][hh]), "+v"(W[u][2][hh]));
                asm("v_permlane16_swap_b32 %0, %1" : "+v"(W[u][1][hh]), "+v"(W[u][3][hh]));
                asm("v_permlane32_swap_b32 %0, %1" : "+v"(W[u][1][hh]), "+v"(W[u][3][hh]));
            }

        // O += P V ; l += P 1  (vf shared across both q-groups)
#pragma unroll
        for (int ks = 0; ks < 2; ++ks) {
            bf16x8 vf[4];
#pragma unroll
            for (int nd = 0; nd < 4; ++nd) {
                int row = nd * 16 + ln;
                vf[nd] = *(const bf16x8*)&Vti[row * 64 + ((ks * 4 + g) ^ (ln & 7)) * 8];
            }
            __builtin_amdgcn_s_setprio(1);
#pragma unroll
            for (int u = 0; u < 2; ++u) {
                union { unsigned uw[4]; bf16x8 v; } pf;
                pf.uw[0] = W[u][2 * ks][0];     pf.uw[1] = W[u][2 * ks][1];
                pf.uw[2] = W[u][2 * ks + 1][0]; pf.uw[3] = W[u][2 * ks + 1][1];
                lacc[u] = MFMA16(pf.v, ones, lacc[u]);
#pragma unroll
                for (int nd = 0; nd < 4; ++nd)
                    oacc[u][nd] = MFMA16(pf.v, vf[nd], oacc[u][nd]);
            }
            __builtin_amdgcn_s_setprio(0);
        }
        __syncthreads();   // drains t+1 KV loads; buffer swap safe
    }

    // Combine the two KV-half partials: group 0 spills fp32 partials to LDS
    // (O_sh padded [64][132] to keep writes ~conflict-free), group 1 adds,
    // normalizes by l_A + l_B and stores.
    if (h == 0) {
#pragma unroll
        for (int u = 0; u < 2; ++u) {
#pragma unroll
            for (int nd = 0; nd < 4; ++nd)
                *(f32x4*)&O_sh[(nd * 16 + ln) * 132 + wl * 32 + u * 16 + g * 4] =
                    oacc[u][nd];
            if (ln == 0)
                *(f32x4*)&l_sh[wl * 32 + u * 16 + g * 4] = lacc[u];
        }
    }
    __syncthreads();
    if (h == 1) {
#pragma unroll
        for (int u = 0; u < 2; ++u) {
            f32x4 l4 = *(const f32x4*)&l_sh[wl * 32 + u * 16 + g * 4];
            f32x4 inv;
#pragma unroll
            for (int r = 0; r < 4; ++r) inv[r] = 1.0f / (lacc[u][r] + l4[r]);
#pragma unroll
            for (int nd = 0; nd < 4; ++nd) {
                f32x4 o4 = *(const f32x4*)&O_sh[(nd * 16 + ln) * 132
                                                + wl * 32 + u * 16 + g * 4];
#pragma unroll
                for (int r = 0; r < 4; ++r) {
                    size_t row = rowQ0 + wl * 32 + u * 16 + g * 4 + r;
                    Ctx[row * 1024 + hcol + nd * 16 + ln] =
                        (bf16)((oacc[u][nd][r] + o4[r]) * inv[r]);
                }
            }
        }
    }
}

extern "C" void kernel_launch(void* const* d_in, const int* in_sizes, int n_in,
                              void* d_out, int out_size, void* d_ws, size_t ws_size,
                              hipStream_t stream)
{
    const float* q  = (const float*)d_in[0];
    const float* k  = (const float*)d_in[1];
    const float* v  = (const float*)d_in[2];
    const float* wq = (const float*)d_in[3];
    const float* bq = (const float*)d_in[4];
    const float* wk = (const float*)d_in[5];
    const float* bk = (const float*)d_in[6];
    const float* wv = (const float*)d_in[7];
    const float* bv = (const float*)d_in[8];
    const float* wo = (const float*)d_in[9];
    const float* bo = (const float*)d_in[10];
    float* out = (float*)d_out;

    const int D = 1024;
    bf16* W  = (bf16*)d_ws;
    bf16* Qp = W;                            // 8 MB
    bf16* Kp = W + (1u << 22);               // 8 MB
    bf16* Vt = W + (2u << 22);               // 8 MB, [bh][d][tok']
    bf16* Ctx = Qp;   // alias: each attn block overwrites only its consumed Q

    if (ws_size >= (size_t)40 * 1024 * 1024) {
        // fast path: everything bf16 up front
        bf16* vb  = W + (3u << 22);          // 8 MB
        bf16* wqb = W + (1u << 24);          // 2 MB
        bf16* wkb = wqb + (1u << 20);
        bf16* wvb = wkb + (1u << 20);
        bf16* wob = wvb + (1u << 20);
        bf16* qb  = (bf16*)d_out;            // d_out scratch (overwritten later)
        bf16* kb  = qb + (1u << 22);

        cvt7_kernel<<<dim3(2048, 4), 256, 0, stream>>>(
            q, qb, k, kb, v, vb, wq, wqb, wk, wkb, wv, wvb, wo, wob);
        qkv_bf16<<<768, 256, 0, stream>>>(qb, kb, vb, wqb, bq, wkb, bk, wvb, bv,
                                          Qp, Kp, Vt);
        attn_kernel<<<512, 512, 0, stream>>>(Qp, Kp, Vt, Ctx);
        gemm_out<<<512, 256, 0, stream>>>(Ctx, wob, bo, out);
    } else {
        // fallback (ws < 40 MB): r7 structure
        bf16* wqb = (bf16*)d_out;
        bf16* wkb = wqb + (size_t)D * D;
        bf16* wvb = wkb + (size_t)D * D;
        bf16* wob = Kp;                      // dead after attn

        cvt3_kernel<<<dim3(512, 3), 256, 0, stream>>>(wq, wqb, wk, wkb, wv, wvb);
        qkv_gemm<<<768, 256, 0, stream>>>(q, k, v, wqb, bq, wkb, bk, wvb, bv,
                                          Qp, Kp, Vt);
        attn_kernel<<<512, 512, 0, stream>>>(Qp, Kp, Vt, Ctx);
        cvt_kernel<<<512, 256, 0, stream>>>(wo, wob, D * D);
        gemm_out<<<512, 256, 0, stream>>>(Ctx, wob, bo, out);
    }
}

// Round 11
// 194.442 us; speedup vs baseline: 1.0288x; 1.0288x over previous
//
#include <hip/hip_runtime.h>

typedef __bf16 bf16;
typedef __bf16 bf16x2 __attribute__((ext_vector_type(2)));
typedef __bf16 bf16x4 __attribute__((ext_vector_type(4)));
typedef __bf16 bf16x8 __attribute__((ext_vector_type(8)));
typedef float f32x4 __attribute__((ext_vector_type(4)));

#define MFMA16(a, b, c) __builtin_amdgcn_mfma_f32_16x16x32_bf16((a), (b), (c), 0, 0, 0)

// 0.125 (attn scale) * log2(e): folded into Q projection so softmax is exp2(s).
#define QSCALE 0.18033688011112042f

// async global->LDS, 16 B per lane. LDS dest = wave-uniform base + lane*16.
__device__ inline void gld16(const void* g, void* l) {
    __builtin_amdgcn_global_load_lds(
        (const __attribute__((address_space(1))) unsigned int*)g,
        (__attribute__((address_space(3))) unsigned int*)l, 16, 0, 0);
}

__device__ inline bf16x8 cvt8(float4 a, float4 b) {
    bf16x8 v;
    v[0] = (bf16)a.x; v[1] = (bf16)a.y; v[2] = (bf16)a.z; v[3] = (bf16)a.w;
    v[4] = (bf16)b.x; v[5] = (bf16)b.y; v[6] = (bf16)b.z; v[7] = (bf16)b.w;
    return v;
}

// ---------------------------------------------------------------------------
// fp32 -> bf16: grid dim3(2048,4), every block full (no dead blocks).
// y=0,1,2 -> q,k,v (4M elems each). y=3 -> the four 1M-elem weights packed:
// wsel = i>>20 picks wq/wk/wv/wo.
// ---------------------------------------------------------------------------
__global__ __launch_bounds__(256) void cvt7_kernel(
    const float* __restrict__ q,  bf16* __restrict__ qb,
    const float* __restrict__ k,  bf16* __restrict__ kb,
    const float* __restrict__ v,  bf16* __restrict__ vb,
    const float* __restrict__ wq, bf16* __restrict__ wqb,
    const float* __restrict__ wk, bf16* __restrict__ wkb,
    const float* __restrict__ wv, bf16* __restrict__ wvb,
    const float* __restrict__ wo, bf16* __restrict__ wob)
{
    int i = (blockIdx.x * 256 + threadIdx.x) * 8;
    const float* src; bf16* dst;
    switch (blockIdx.y) {
        case 0: src = q; dst = qb; break;
        case 1: src = k; dst = kb; break;
        case 2: src = v; dst = vb; break;
        default: {
            int wsel = i >> 20;                 // 0..3
            int off  = i & ((1 << 20) - 1);
            src = wsel == 0 ? wq : wsel == 1 ? wk : wsel == 2 ? wv : wo;
            dst = wsel == 0 ? wqb : wsel == 1 ? wkb : wsel == 2 ? wvb : wob;
            float4 a = *(const float4*)&src[off];
            float4 b = *(const float4*)&src[off + 4];
            *(bf16x8*)&dst[off] = cvt8(a, b);
            return;
        }
    }
    float4 a = *(const float4*)&src[i];
    float4 b = *(const float4*)&src[i + 4];
    *(bf16x8*)&dst[i] = cvt8(a, b);
}

__global__ __launch_bounds__(256) void cvt3_kernel(
    const float* __restrict__ s0, bf16* __restrict__ d0,
    const float* __restrict__ s1, bf16* __restrict__ d1,
    const float* __restrict__ s2, bf16* __restrict__ d2)
{
    const float* src = blockIdx.y == 0 ? s0 : blockIdx.y == 1 ? s1 : s2;
    bf16*        dst = blockIdx.y == 0 ? d0 : blockIdx.y == 1 ? d1 : d2;
    int i = (blockIdx.x * 256 + threadIdx.x) * 8;
    float4 a = *(const float4*)&src[i];
    float4 b = *(const float4*)&src[i + 4];
    *(bf16x8*)&dst[i] = cvt8(a, b);
}

__global__ __launch_bounds__(256) void cvt_kernel(
    const float* __restrict__ src, bf16* __restrict__ dst, int n)
{
    int i = (blockIdx.x * 256 + threadIdx.x) * 8;
    if (i < n) {
        float4 a = *(const float4*)&src[i];
        float4 b = *(const float4*)&src[i + 4];
        *(bf16x8*)&dst[i] = cvt8(a, b);
    }
}

// ---------------------------------------------------------------------------
// Pure-bf16 fused QKV projection (fast path), m97-form: both operands staged
// with global_load_lds into single-buffered swizzled LDS, 2 barriers/iter;
// latency hidden by cross-block overlap. Grid 768 XCD-swizzled.
// proj0 -> Qp (scaled), proj1 -> Kp, proj2 -> Vt[bh][d][t64*64+kv'],
// kv' = (s&15)*4 + (s>>4), via LDS transpose.
// ---------------------------------------------------------------------------
__global__ __launch_bounds__(256) void qkv_bf16(
    const bf16* __restrict__ qb, const bf16* __restrict__ kb,
    const bf16* __restrict__ vb,
    const bf16* __restrict__ wq, const float* __restrict__ bq,
    const bf16* __restrict__ wk, const float* __restrict__ bk,
    const bf16* __restrict__ wv, const float* __restrict__ bv,
    bf16* __restrict__ Qp, bf16* __restrict__ Kp, bf16* __restrict__ Vt)
{
    __shared__ __align__(16) bf16 sm[16896];   // As(8192)+Bs(8192); Ts alias 16896
    bf16* As = sm;
    bf16* Bs = sm + 8192;
    bf16* Ts = sm;                             // epilogue transpose [128][132]

    const int id  = blockIdx.x;
    const int pr  = (id >> 6) * 8 + (id & 7);  // proj*32+row, 0..95
    const int proj = pr >> 5;
    const int m0  = (pr & 31) * 128;
    const int n0  = ((id >> 3) & 7) * 128;

    const bf16*  A    = proj == 0 ? qb : proj == 1 ? kb : vb;
    const bf16*  B    = proj == 0 ? wq : proj == 1 ? wk : wv;
    const float* bias = proj == 0 ? bq : proj == 1 ? bk : bv;

    const int tid  = threadIdx.x;
    const int lane = tid & 63;
    const int w    = tid >> 6;
    const int g    = lane >> 4;
    const int ln   = lane & 15;
    const int rowb = (w & 1) * 64;
    const int colb = (w >> 1) * 64;
    const int ro   = lane >> 3, lc = lane & 7;

    auto issue = [&](int t) {
        int k0 = t * 64;
        for (int j = 0; j < 4; ++j) {
            int base = w * 32 + j * 8;
            int row  = base + ro;
            int c    = lc ^ (row & 7);
            gld16(&A[(size_t)(m0 + row) * 1024 + k0 + c * 8], &As[base * 64]);
            gld16(&B[(size_t)(n0 + row) * 1024 + k0 + c * 8], &Bs[base * 64]);
        }
    };

    issue(0);
    f32x4 acc[4][4] = {};

    for (int t = 0; t < 16; ++t) {
        __syncthreads();                 // drains gld(t): LDS valid
        for (int ks = 0; ks < 2; ++ks) {
            bf16x8 af[4], bfm[4];
            for (int mi = 0; mi < 4; ++mi) {
                int row = rowb + mi * 16 + ln;
                af[mi] = *(const bf16x8*)&As[row * 64 + ((ks * 4 + g) ^ (ln & 7)) * 8];
            }
            for (int ni = 0; ni < 4; ++ni) {
                int row = colb + ni * 16 + ln;
                bfm[ni] = *(const bf16x8*)&Bs[row * 64 + ((ks * 4 + g) ^ (ln & 7)) * 8];
            }
            for (int mi = 0; mi < 4; ++mi)
                for (int ni = 0; ni < 4; ++ni)
                    acc[mi][ni] = MFMA16(af[mi], bfm[ni], acc[mi][ni]);
        }
        __syncthreads();                 // all waves done reading tile t
        if (t < 15) issue(t + 1);
    }

    if (proj != 2) {
        for (int mi = 0; mi < 4; ++mi) {
            for (int ni = 0; ni < 4; ++ni) {
                int col = n0 + colb + ni * 16 + ln;
                float bv_ = bias[col];
                int rowbase = m0 + rowb + mi * 16 + g * 4;
                if (proj == 0) {
                    for (int r = 0; r < 4; ++r)
                        Qp[(size_t)(rowbase + r) * 1024 + col] =
                            (bf16)((acc[mi][ni][r] + bv_) * QSCALE);
                } else {
                    for (int r = 0; r < 4; ++r)
                        Kp[(size_t)(rowbase + r) * 1024 + col] =
                            (bf16)(acc[mi][ni][r] + bv_);
                }
            }
        }
    } else {
        for (int mi = 0; mi < 4; ++mi) {
            for (int ni = 0; ni < 4; ++ni) {
                int col = colb + ni * 16 + ln;
                float bv_ = bias[n0 + col];
                int row = rowb + mi * 16 + g * 4;
                bf16x4 pk;
                for (int r = 0; r < 4; ++r) pk[r] = (bf16)(acc[mi][ni][r] + bv_);
                *(bf16x4*)&Ts[col * 132 + row] = pk;
            }
        }
        __syncthreads();
        const int bidx = m0 >> 11;
        const int tok0 = m0 & 2047;
        for (int i = 0; i < 8; ++i) {
            int c    = tid + 256 * i;
            int col  = c >> 4;
            int t64  = (c >> 3) & 1;
            int cc   = c & 7;
            int gcol = n0 + col;
            union { bf16 e[8]; uint4 u; } tmp;
            for (int j = 0; j < 8; ++j) {
                int s = 2 * cc + (j >> 2) + ((j & 3) << 4);
                tmp.e[j] = Ts[col * 132 + t64 * 64 + s];
            }
            size_t dst = ((size_t)(bidx * 16 + (gcol >> 6)) * 64 + (gcol & 63)) * 2048
                         + tok0 + t64 * 64 + cc * 8;
            *(uint4*)&Vt[dst] = tmp.u;
        }
    }
}

// ---------------------------------------------------------------------------
// Fallback QKV (ws too small): r7's fp32-A register staging + bf16-B gld16.
// ---------------------------------------------------------------------------
__global__ __launch_bounds__(256) void qkv_gemm(
    const float* __restrict__ q, const float* __restrict__ k,
    const float* __restrict__ v,
    const bf16* __restrict__ wq, const float* __restrict__ bq,
    const bf16* __restrict__ wk, const float* __restrict__ bk,
    const bf16* __restrict__ wv, const float* __restrict__ bv,
    bf16* __restrict__ Qp, bf16* __restrict__ Kp, bf16* __restrict__ Vt)
{
    __shared__ __align__(16) bf16 sm[8192 + 2 * 8192];
    bf16* As = sm;
    bf16* Bs = sm + 8192;
    bf16* Ts = sm;

    const int id  = blockIdx.x;
    const int pr  = (id >> 6) * 8 + (id & 7);
    const int proj = pr >> 5;
    const int m0  = (pr & 31) * 128;
    const int n0  = ((id >> 3) & 7) * 128;

    const float* A    = proj == 0 ? q  : proj == 1 ? k  : v;
    const bf16*  B    = proj == 0 ? wq : proj == 1 ? wk : wv;
    const float* bias = proj == 0 ? bq : proj == 1 ? bk : bv;

    const int tid  = threadIdx.x;
    const int lane = tid & 63;
    const int w    = tid >> 6;
    const int g    = lane >> 4;
    const int ln   = lane & 15;
    const int rowb = (w & 1) * 64;
    const int colb = (w >> 1) * 64;
    const int srow = tid >> 3, slc = tid & 7;
    const int ro   = lane >> 3, lc = lane & 7;

    float4 ra[4][2];
    for (int i = 0; i < 4; ++i) {
        const float* p = &A[(size_t)(m0 + srow + 32 * i) * 1024 + slc * 8];
        ra[i][0] = *(const float4*)p;
        ra[i][1] = *(const float4*)(p + 4);
    }
    for (int j = 0; j < 4; ++j) {
        int base = w * 32 + j * 8;
        int row  = base + ro;
        int c    = lc ^ (row & 7);
        gld16(&B[(size_t)(n0 + row) * 1024 + c * 8], &Bs[base * 64]);
    }

    f32x4 acc[4][4] = {};

    for (int t = 0; t < 16; ++t) {
        __syncthreads();
        for (int i = 0; i < 4; ++i) {
            int row = srow + 32 * i;
            *(bf16x8*)&As[row * 64 + (slc ^ (row & 7)) * 8] = cvt8(ra[i][0], ra[i][1]);
        }
        __syncthreads();
        if (t < 15) {
            int k1 = (t + 1) * 64;
            for (int i = 0; i < 4; ++i) {
                const float* p = &A[(size_t)(m0 + srow + 32 * i) * 1024 + k1 + slc * 8];
                ra[i][0] = *(const float4*)p;
                ra[i][1] = *(const float4*)(p + 4);
            }
            int bsel = (t + 1) & 1;
            for (int j = 0; j < 4; ++j) {
                int base = w * 32 + j * 8;
                int row  = base + ro;
                int c    = lc ^ (row & 7);
                gld16(&B[(size_t)(n0 + row) * 1024 + k1 + c * 8],
                      &Bs[bsel * 8192 + base * 64]);
            }
        }
        const bf16* Bt = Bs + (t & 1) * 8192;
        for (int ks = 0; ks < 2; ++ks) {
            bf16x8 af[4], bfm[4];
            for (int mi = 0; mi < 4; ++mi) {
                int row = rowb + mi * 16 + ln;
                af[mi] = *(const bf16x8*)&As[row * 64 + ((ks * 4 + g) ^ (ln & 7)) * 8];
            }
            for (int ni = 0; ni < 4; ++ni) {
                int row = colb + ni * 16 + ln;
                bfm[ni] = *(const bf16x8*)&Bt[row * 64 + ((ks * 4 + g) ^ (ln & 7)) * 8];
            }
            for (int mi = 0; mi < 4; ++mi)
                for (int ni = 0; ni < 4; ++ni)
                    acc[mi][ni] = MFMA16(af[mi], bfm[ni], acc[mi][ni]);
        }
    }

    if (proj != 2) {
        for (int mi = 0; mi < 4; ++mi) {
            for (int ni = 0; ni < 4; ++ni) {
                int col = n0 + colb + ni * 16 + ln;
                float bv_ = bias[col];
                int rowbase = m0 + rowb + mi * 16 + g * 4;
                if (proj == 0) {
                    for (int r = 0; r < 4; ++r)
                        Qp[(size_t)(rowbase + r) * 1024 + col] =
                            (bf16)((acc[mi][ni][r] + bv_) * QSCALE);
                } else {
                    for (int r = 0; r < 4; ++r)
                        Kp[(size_t)(rowbase + r) * 1024 + col] =
                            (bf16)(acc[mi][ni][r] + bv_);
                }
            }
        }
    } else {
        __syncthreads();
        for (int mi = 0; mi < 4; ++mi) {
            for (int ni = 0; ni < 4; ++ni) {
                int col = colb + ni * 16 + ln;
                float bv_ = bias[n0 + col];
                int row = rowb + mi * 16 + g * 4;
                bf16x4 pk;
                for (int r = 0; r < 4; ++r) pk[r] = (bf16)(acc[mi][ni][r] + bv_);
                *(bf16x4*)&Ts[col * 132 + row] = pk;
            }
        }
        __syncthreads();
        const int bidx = m0 >> 11;
        const int tok0 = m0 & 2047;
        for (int i = 0; i < 8; ++i) {
            int c    = tid + 256 * i;
            int col  = c >> 4;
            int t64  = (c >> 3) & 1;
            int cc   = c & 7;
            int gcol = n0 + col;
            union { bf16 e[8]; uint4 u; } tmp;
            for (int j = 0; j < 8; ++j) {
                int s = 2 * cc + (j >> 2) + ((j & 3) << 4);
                tmp.e[j] = Ts[col * 132 + t64 * 64 + s];
            }
            size_t dst = ((size_t)(bidx * 16 + (gcol >> 6)) * 64 + (gcol & 63)) * 2048
                         + tok0 + t64 * 64 + cc * 8;
            *(uint4*)&Vt[dst] = tmp.u;
        }
    }
}

// ---------------------------------------------------------------------------
// Output projection: C[4096,1024] fp32 = Ctx(bf16) @ wo^T(bf16) + bo.
// 64x128 tiles, grid 512, both operands dbuf global_load_lds, 1 barrier/iter.
// ---------------------------------------------------------------------------
__global__ __launch_bounds__(256) void gemm_out(
    const bf16* __restrict__ A, const bf16* __restrict__ B,
    const float* __restrict__ bias, float* __restrict__ C)
{
    __shared__ __align__(16) bf16 sm[2 * 4096 + 2 * 8192];
    bf16* As = sm;
    bf16* Bs = sm + 8192;

    const int id = blockIdx.x;
    const int m0 = ((id >> 6) * 8 + (id & 7)) * 64;
    const int n0 = ((id >> 3) & 7) * 128;

    const int tid  = threadIdx.x;
    const int lane = tid & 63;
    const int w    = tid >> 6;
    const int g    = lane >> 4;
    const int ln   = lane & 15;
    const int rowb = (w & 1) * 32;
    const int colb = (w >> 1) * 64;
    const int ro   = lane >> 3, lc = lane & 7;

    auto issue = [&](int t) {
        int k0 = t * 64, sel = t & 1;
        for (int j = 0; j < 2; ++j) {
            int base = w * 16 + j * 8;
            int row  = base + ro;
            int c    = lc ^ (row & 7);
            gld16(&A[(size_t)(m0 + row) * 1024 + k0 + c * 8],
                  &As[sel * 4096 + base * 64]);
        }
        for (int j = 0; j < 4; ++j) {
            int base = w * 32 + j * 8;
            int row  = base + ro;
            int c    = lc ^ (row & 7);
            gld16(&B[(size_t)(n0 + row) * 1024 + k0 + c * 8],
                  &Bs[sel * 8192 + base * 64]);
        }
    };

    issue(0);
    f32x4 acc[2][4] = {};

    for (int t = 0; t < 16; ++t) {
        __syncthreads();
        if (t < 15) issue(t + 1);
        const bf16* At = As + (t & 1) * 4096;
        const bf16* Bt = Bs + (t & 1) * 8192;
        for (int ks = 0; ks < 2; ++ks) {
            bf16x8 af[2], bfm[4];
            for (int mi = 0; mi < 2; ++mi) {
                int row = rowb + mi * 16 + ln;
                af[mi] = *(const bf16x8*)&At[row * 64 + ((ks * 4 + g) ^ (ln & 7)) * 8];
            }
            for (int ni = 0; ni < 4; ++ni) {
                int row = colb + ni * 16 + ln;
                bfm[ni] = *(const bf16x8*)&Bt[row * 64 + ((ks * 4 + g) ^ (ln & 7)) * 8];
            }
            for (int mi = 0; mi < 2; ++mi)
                for (int ni = 0; ni < 4; ++ni)
                    acc[mi][ni] = MFMA16(af[mi], bfm[ni], acc[mi][ni]);
        }
    }

    for (int mi = 0; mi < 2; ++mi) {
        for (int ni = 0; ni < 4; ++ni) {
            int col = n0 + colb + ni * 16 + ln;
            float bv_ = bias[col];
            int rowbase = m0 + rowb + mi * 16 + g * 4;
            for (int r = 0; r < 4; ++r)
                C[(size_t)(rowbase + r) * 1024 + col] = acc[mi][ni][r] + bv_;
        }
    }
}

// ---------------------------------------------------------------------------
// Flash attention (no-max softmax; logits pre-scaled -> exp2). 128-row q-tiles,
// 512-thread blocks: waves 0-3 do KV[0:1024], waves 4-7 KV[1024:2048] for the
// SAME 128 q-rows (partials combine by plain addition in an LDS epilogue).
// Grid 512 XCD-swizzled, 2 blocks/CU (LDS 64 KiB). [R5-proven version]
// ---------------------------------------------------------------------------
__global__ __launch_bounds__(512, 4) void attn_kernel(
    const bf16* __restrict__ Qp, const bf16* __restrict__ Kp,
    const bf16* __restrict__ Vt, bf16* __restrict__ Ctx)
{
    __shared__ __align__(16) bf16 smem[32768];   // 64 KiB
    bf16* Ks = smem;               // [grp*2+sel][64][64]  [kv][d]
    bf16* Vs = smem + 16384;       // [grp*2+sel][64][64]  [d][kv']
    float* O_sh = (float*)smem;            // epilogue alias [64][132]
    float* l_sh = (float*)smem + 64 * 132; // epilogue alias [128]

    const int id = blockIdx.x;                     // 0..511
    const int qt = (id >> 3) & 15;                 // 0..15 (128-row q-tiles)
    const int bh = (id & 7) + ((id >> 7) << 3);    // 0..31, id%8 = XCD

    const int tid  = threadIdx.x;
    const int lane = tid & 63;
    const int w    = tid >> 6;     // 0..7
    const int h    = w >> 2;       // KV half (0: rows 0..1023, 1: 1024..2047)
    const int wl   = w & 3;        // wave within group
    const int g    = lane >> 4;
    const int ln   = lane & 15;
    const int ro   = lane >> 3, lc = lane & 7;
    const int kvb  = h * 1024;
    const size_t rowQ0 = (size_t)(bh >> 4) * 2048 + qt * 128;
    const size_t rowK0 = (size_t)(bh >> 4) * 2048;
    const int hcol = (bh & 15) * 64;
    const bf16* VtB = Vt + (size_t)bh * 64 * 2048;

    // stage KV tile 0 of this group's half (each wave: 16 rows of K and V)
    for (int j = 0; j < 2; ++j) {
        int base = wl * 16 + j * 8;
        int row  = base + ro;
        int c    = lc ^ (row & 7);
        gld16(&Kp[(rowK0 + kvb + row) * 1024 + hcol + c * 8],
              &Ks[(h * 2 + 0) * 4096 + base * 64]);
        gld16(&VtB[(size_t)row * 2048 + kvb + c * 8],
              &Vs[(h * 2 + 0) * 4096 + base * 64]);
    }

    // Q fragments straight from global, two 16-row groups per wave.
    // Both KV-halves load the SAME q-rows (q = wl*32 + u*16 + ln).
    bf16x8 qf[2][2];
#pragma unroll
    for (int u = 0; u < 2; ++u)
#pragma unroll
        for (int ks = 0; ks < 2; ++ks)
            qf[u][ks] = *(const bf16x8*)&Qp[(rowQ0 + wl * 32 + u * 16 + ln) * 1024
                                            + hcol + ks * 32 + g * 8];

    bf16x8 ones;
#pragma unroll
    for (int i = 0; i < 8; ++i) ones[i] = (bf16)1.0f;

    f32x4 oacc[2][4] = {};
    f32x4 lacc[2] = {};

    __syncthreads();

    for (int t = 0; t < 16; ++t) {
        if (t < 15) {                  // t+1 KV flies through this tile's compute
            int sel = (t + 1) & 1, kvo = kvb + (t + 1) * 64;
            for (int j = 0; j < 2; ++j) {
                int base = wl * 16 + j * 8;
                int row  = base + ro;
                int c    = lc ^ (row & 7);
                gld16(&Kp[(rowK0 + kvo + row) * 1024 + hcol + c * 8],
                      &Ks[(h * 2 + sel) * 4096 + base * 64]);
                gld16(&VtB[(size_t)row * 2048 + kvo + c * 8],
                      &Vs[(h * 2 + sel) * 4096 + base * 64]);
            }
        }
        const bf16* Kt  = Ks + (h * 2 + (t & 1)) * 4096;
        const bf16* Vti = Vs + (h * 2 + (t & 1)) * 4096;

        // S^T = K Q^T (pre-scaled): sf[u][nj][r] = S[q=ln(u)][kv=nj*16+g*4+r]
        f32x4 sf[2][4] = {};
#pragma unroll
        for (int ks = 0; ks < 2; ++ks) {
            bf16x8 kf[4];
#pragma unroll
            for (int nj = 0; nj < 4; ++nj) {
                int row = nj * 16 + ln;
                kf[nj] = *(const bf16x8*)&Kt[row * 64 + ((ks * 4 + g) ^ (ln & 7)) * 8];
            }
            __builtin_amdgcn_s_setprio(1);
#pragma unroll
            for (int u = 0; u < 2; ++u)
#pragma unroll
                for (int nj = 0; nj < 4; ++nj)
                    sf[u][nj] = MFMA16(kf[nj], qf[u][ks], sf[u][nj]);
            __builtin_amdgcn_s_setprio(0);
        }

        // P = exp2(S), packed along nj: W[u][r][h] = cvt_pk(p[2h][r], p[2h+1][r])
        unsigned W[2][4][2];
#pragma unroll
        for (int u = 0; u < 2; ++u)
#pragma unroll
            for (int r = 0; r < 4; ++r)
#pragma unroll
                for (int hh = 0; hh < 2; ++hh) {
                    bf16x2 t2;
                    t2[0] = (bf16)__builtin_amdgcn_exp2f(sf[u][2 * hh][r]);
                    t2[1] = (bf16)__builtin_amdgcn_exp2f(sf[u][2 * hh + 1][r]);
                    W[u][r][hh] = __builtin_bit_cast(unsigned, t2);
                }
        // Route to PV A-fragment order (matches Vt token permutation).
#pragma unroll
        for (int u = 0; u < 2; ++u)
#pragma unroll
            for (int hh = 0; hh < 2; ++hh) {
                asm("v_permlane16_swap_b32 %0, %1" : "+v"(W[u][0][hh]), "+v"(W[u][2][hh]));
                asm("v_permlane32_swap_b32 %0, %1" : "+v"(W[u][0][hh]), "+v"(W[u][2][hh]));
                asm("v_permlane16_swap_b32 %0, %1" : "+v"(W[u][1][hh]), "+v"(W[u][3][hh]));
                asm("v_permlane32_swap_b32 %0, %1" : "+v"(W[u][1][hh]), "+v"(W[u][3][hh]));
            }

        // O += P V ; l += P 1  (vf shared across both q-groups)
#pragma unroll
        for (int ks = 0; ks < 2; ++ks) {
            bf16x8 vf[4];
#pragma unroll
            for (int nd = 0; nd < 4; ++nd) {
                int row = nd * 16 + ln;
                vf[nd] = *(const bf16x8*)&Vti[row * 64 + ((ks * 4 + g) ^ (ln & 7)) * 8];
            }
            __builtin_amdgcn_s_setprio(1);
#pragma unroll
            for (int u = 0; u < 2; ++u) {
                union { unsigned uw[4]; bf16x8 v; } pf;
                pf.uw[0] = W[u][2 * ks][0];     pf.uw[1] = W[u][2 * ks][1];
                pf.uw[2] = W[u][2 * ks + 1][0]; pf.uw[3] = W[u][2 * ks + 1][1];
                lacc[u] = MFMA16(pf.v, ones, lacc[u]);
#pragma unroll
                for (int nd = 0; nd < 4; ++nd)
                    oacc[u][nd] = MFMA16(pf.v, vf[nd], oacc[u][nd]);
            }
            __builtin_amdgcn_s_setprio(0);
        }
        __syncthreads();   // drains t+1 KV loads; buffer swap safe
    }

    // Combine the two KV-half partials: group 0 spills fp32 partials to LDS
    // (O_sh padded [64][132] to keep writes ~conflict-free), group 1 adds,
    // normalizes by l_A + l_B and stores.
    if (h == 0) {
#pragma unroll
        for (int u = 0; u < 2; ++u) {
#pragma unroll
            for (int nd = 0; nd < 4; ++nd)
                *(f32x4*)&O_sh[(nd * 16 + ln) * 132 + wl * 32 + u * 16 + g * 4] =
                    oacc[u][nd];
            if (ln == 0)
                *(f32x4*)&l_sh[wl * 32 + u * 16 + g * 4] = lacc[u];
        }
    }
    __syncthreads();
    if (h == 1) {
#pragma unroll
        for (int u = 0; u < 2; ++u) {
            f32x4 l4 = *(const f32x4*)&l_sh[wl * 32 + u * 16 + g * 4];
            f32x4 inv;
#pragma unroll
            for (int r = 0; r < 4; ++r) inv[r] = 1.0f / (lacc[u][r] + l4[r]);
#pragma unroll
            for (int nd = 0; nd < 4; ++nd) {
                f32x4 o4 = *(const f32x4*)&O_sh[(nd * 16 + ln) * 132
                                                + wl * 32 + u * 16 + g * 4];
#pragma unroll
                for (int r = 0; r < 4; ++r) {
                    size_t row = rowQ0 + wl * 32 + u * 16 + g * 4 + r;
                    Ctx[row * 1024 + hcol + nd * 16 + ln] =
                        (bf16)((oacc[u][nd][r] + o4[r]) * inv[r]);
                }
            }
        }
    }
}

extern "C" void kernel_launch(void* const* d_in, const int* in_sizes, int n_in,
                              void* d_out, int out_size, void* d_ws, size_t ws_size,
                              hipStream_t stream)
{
    const float* q  = (const float*)d_in[0];
    const float* k  = (const float*)d_in[1];
    const float* v  = (const float*)d_in[2];
    const float* wq = (const float*)d_in[3];
    const float* bq = (const float*)d_in[4];
    const float* wk = (const float*)d_in[5];
    const float* bk = (const float*)d_in[6];
    const float* wv = (const float*)d_in[7];
    const float* bv = (const float*)d_in[8];
    const float* wo = (const float*)d_in[9];
    const float* bo = (const float*)d_in[10];
    float* out = (float*)d_out;

    const int D = 1024;
    bf16* W  = (bf16*)d_ws;
    bf16* Qp = W;                            // 8 MB
    bf16* Kp = W + (1u << 22);               // 8 MB
    bf16* Vt = W + (2u << 22);               // 8 MB, [bh][d][tok']
    bf16* Ctx = Qp;   // alias: each attn block overwrites only its consumed Q

    if (ws_size >= (size_t)40 * 1024 * 1024) {
        // fast path: everything bf16 up front
        bf16* vb  = W + (3u << 22);          // 8 MB
        bf16* wqb = W + (1u << 24);          // 2 MB
        bf16* wkb = wqb + (1u << 20);
        bf16* wvb = wkb + (1u << 20);
        bf16* wob = wvb + (1u << 20);
        bf16* qb  = (bf16*)d_out;            // d_out scratch (overwritten later)
        bf16* kb  = qb + (1u << 22);

        cvt7_kernel<<<dim3(2048, 4), 256, 0, stream>>>(
            q, qb, k, kb, v, vb, wq, wqb, wk, wkb, wv, wvb, wo, wob);
        qkv_bf16<<<768, 256, 0, stream>>>(qb, kb, vb, wqb, bq, wkb, bk, wvb, bv,
                                          Qp, Kp, Vt);
        attn_kernel<<<512, 512, 0, stream>>>(Qp, Kp, Vt, Ctx);
        gemm_out<<<512, 256, 0, stream>>>(Ctx, wob, bo, out);
    } else {
        // fallback (ws < 40 MB): r7 structure
        bf16* wqb = (bf16*)d_out;
        bf16* wkb = wqb + (size_t)D * D;
        bf16* wvb = wkb + (size_t)D * D;
        bf16* wob = Kp;                      // dead after attn

        cvt3_kernel<<<dim3(512, 3), 256, 0, stream>>>(wq, wqb, wk, wkb, wv, wvb);
        qkv_gemm<<<768, 256, 0, stream>>>(q, k, v, wqb, bq, wkb, bk, wvb, bv,
                                          Qp, Kp, Vt);
        attn_kernel<<<512, 512, 0, stream>>>(Qp, Kp, Vt, Ctx);
        cvt_kernel<<<512, 256, 0, stream>>>(wo, wob, D * D);
        gemm_out<<<512, 256, 0, stream>>>(Ctx, wob, bo, out);
    }
}